// Round 1
// 346.186 us; speedup vs baseline: 1.0244x; 1.0244x over previous
//
#include <hip/hip_runtime.h>
#include <math.h>

#define MASK_SIZE 28
#define MASK_PIX (MASK_SIZE * MASK_SIZE)
// Shapes fixed by reference setup_inputs(): P=512, G=200, H=520, W=704.
#define GT_H 520
#define GT_W 704

// ws layout (first 16 B zeroed via hipMemsetAsync each launch):
//   wsf[0] = loss sum (float); wsi[1] = num_pos (int); wsi[2] = blocks-done counter (int)

__global__ __launch_bounds__(256) void fused_kernel(
        const float* __restrict__ mask_logits,
        const float* __restrict__ proposals,
        const float* __restrict__ gt_boxes,
        const float* __restrict__ gt_masks,
        int G, int H, int W, int nblocks,
        float* __restrict__ wssum,
        int* __restrict__ wsnpos,
        int* __restrict__ wsdone,
        float* __restrict__ out) {
    const int p = blockIdx.x;
    const int tid = threadIdx.x;

    // ---- Phase 1: argmax IoU for proposal p over G gt boxes (threads split G) ----
    const float ax1 = proposals[p * 4 + 0], ay1 = proposals[p * 4 + 1];
    const float ax2 = proposals[p * 4 + 2], ay2 = proposals[p * 4 + 3];
    const float area_a = (ax2 - ax1) * (ay2 - ay1);

    float best = -1.0f;
    int bidx = 0x7fffffff;
    for (int j = tid; j < G; j += blockDim.x) {
        float bx1 = gt_boxes[j * 4 + 0], by1 = gt_boxes[j * 4 + 1];
        float bx2 = gt_boxes[j * 4 + 2], by2 = gt_boxes[j * 4 + 3];
        float area_b = (bx2 - bx1) * (by2 - by1);
        float lx = fmaxf(ax1, bx1), ly = fmaxf(ay1, by1);
        float rx = fminf(ax2, bx2), ry = fminf(ay2, by2);
        float w = fmaxf(rx - lx, 0.0f), h = fmaxf(ry - ly, 0.0f);
        float inter = w * h;
        float iou = inter / (area_a + area_b - inter);
        // strict > within a thread; j strictly increases so first-occurrence holds
        if (iou > best) { best = iou; bidx = j; }
    }
    // wave-64 argmax reduce with first-occurrence tie-break (min index on equal iou)
    for (int off = 32; off > 0; off >>= 1) {
        float ob = __shfl_down(best, off, 64);
        int   oi = __shfl_down(bidx, off, 64);
        if (ob > best || (ob == best && oi < bidx)) { best = ob; bidx = oi; }
    }
    __shared__ float sbest[4];
    __shared__ int   sbidx[4];
    const int wid = tid >> 6;
    if ((tid & 63) == 0) { sbest[wid] = best; sbidx[wid] = bidx; }
    __syncthreads();
    {
        best = sbest[0]; bidx = sbidx[0];
        const int nw = blockDim.x >> 6;
        for (int w2 = 1; w2 < nw; ++w2) {
            if (sbest[w2] > best || (sbest[w2] == best && sbidx[w2] < bidx)) {
                best = sbest[w2]; bidx = sbidx[w2];
            }
        }
    }
    const int pos = (best > 0.3f) ? 1 : 0;

    // ---- Phase 2: bilinear target extraction + BCE (positives only) ----
    float lsum = 0.0f;
    if (pos) {
        const int g = bidx;
        float bx1f = gt_boxes[g * 4 + 0], by1f = gt_boxes[g * 4 + 1];
        float bx2f = gt_boxes[g * 4 + 2], by2f = gt_boxes[g * 4 + 3];
        int b0 = (int)bx1f, b1 = (int)by1f, b2 = (int)bx2f, b3 = (int)by2f;
        int x1 = min(max(b0, 0), W - 1);
        int y1 = min(max(b1, 0), H - 1);
        int x2 = max(x1 + 1, min(b2, W));
        int y2 = max(y1 + 1, min(b3, H));
        float cw = (float)(x2 - x1), ch = (float)(y2 - y1);
        const float* mrow = gt_masks + (size_t)g * H * W;

        for (int i = tid; i < MASK_PIX; i += blockDim.x) {
            int py = i / MASK_SIZE, px = i - py * MASK_SIZE;
            float sy = fminf(fmaxf(((float)py + 0.5f) * ch / (float)MASK_SIZE - 0.5f, 0.0f), ch - 1.0f);
            float sx = fminf(fmaxf(((float)px + 0.5f) * cw / (float)MASK_SIZE - 0.5f, 0.0f), cw - 1.0f);
            int y0 = (int)floorf(sy);
            int x0 = (int)floorf(sx);
            int yp = min(y0 + 1, (y2 - y1) - 1);
            int xp = min(x0 + 1, (x2 - x1) - 1);
            float wy = sy - (float)y0;
            float wx = sx - (float)x0;
            int Y0 = y1 + y0, Y1 = y1 + yp, X0 = x1 + x0, X1 = x1 + xp;
            float t00 = mrow[Y0 * W + X0];
            float t01 = mrow[Y0 * W + X1];
            float t10 = mrow[Y1 * W + X0];
            float t11 = mrow[Y1 * W + X1];
            float tgt = (1.0f - wy) * (1.0f - wx) * t00 + (1.0f - wy) * wx * t01
                      + wy * (1.0f - wx) * t10 + wy * wx * t11;
            float l = mask_logits[((size_t)p * 2 + 1) * MASK_PIX + i];
            // jax.nn.softplus stable form: max(x,0) + log1p(exp(-|x|))
            float bce = fmaxf(l, 0.0f) + log1pf(expf(-fabsf(l))) - l * tgt;
            lsum += bce;
        }
    }

    // ---- block reduce of lsum ----
    for (int off = 32; off > 0; off >>= 1) lsum += __shfl_down(lsum, off, 64);
    __shared__ float swave[4];
    if ((tid & 63) == 0) swave[wid] = lsum;
    __syncthreads();

    // ---- accumulate + last-block finalize (completion counter, no spin) ----
    if (tid == 0) {
        if (pos) {
            float tot = 0.0f;
            const int nw = blockDim.x >> 6;
            for (int w2 = 0; w2 < nw; ++w2) tot += swave[w2];
            atomicAdd(wssum, tot);   // device-scope by default on CDNA
            atomicAdd(wsnpos, 1);
        }
        __threadfence();             // order my sum/npos atomics before the done-counter bump
        int done = atomicAdd(wsdone, 1);
        if (done == nblocks - 1) {
            // all other blocks have fenced + completed their atomics
            float s = atomicAdd(wssum, 0.0f);   // coherent read via atomic RMW
            int  np = atomicAdd(wsnpos, 0);
            float denom = fmaxf((float)np, 1.0f) * (float)MASK_PIX;
            out[0] = (np > 0) ? (s / denom) : 0.0f;
        }
    }
}

extern "C" void kernel_launch(void* const* d_in, const int* in_sizes, int n_in,
                              void* d_out, int out_size, void* d_ws, size_t ws_size,
                              hipStream_t stream) {
    const float* mask_logits = (const float*)d_in[0];  // (P,2,28,28) f32
    const float* proposals   = (const float*)d_in[1];  // (P,4) f32
    const float* gt_boxes    = (const float*)d_in[2];  // (G,4) f32
    const float* gt_masks    = (const float*)d_in[3];  // (G,H,W) f32
    // d_in[4] = gt_labels (unused by reference math)
    float* out = (float*)d_out;

    int P = in_sizes[1] / 4;
    int G = in_sizes[2] / 4;

    float* wsf = (float*)d_ws;
    int* wsi = (int*)d_ws;

    // zero the 16-byte accumulator block (ws is poisoned 0xAA every launch).
    // hipMemsetAsync on the capture stream becomes a graph memset node — capture-safe.
    hipMemsetAsync(d_ws, 0, 16, stream);

    fused_kernel<<<P, 256, 0, stream>>>(mask_logits, proposals, gt_boxes, gt_masks,
                                        G, GT_H, GT_W, P,
                                        &wsf[0], &wsi[1], &wsi[2], out);
}